// Round 10
// baseline (151.766 us; speedup 1.0000x reference)
//
#include <hip/hip_runtime.h>
#include <hip/hip_bf16.h>

#define MPTS 50000
#define NPTS 100000
#define KK 15
#define TM 16      // queries per tile; 8 waves, wave owns 2 -> barrier-free A/B phases
#define NTILES (MPTS / TM)   // 3125
#define PGRID 768            // persistent grid: 3 blocks/CU (LDS 53440 -> 3 fit)
#define WTP 1028   // wtw row stride (shorts): 514 b32 = 2 mod 32 -> phase-C A reads uniform banks
#define STP 36     // weight-row stride inside wtw (shorts)
#define STPH 20    // half-h stage row stride (shorts): 40 B rows (8B-aligned)

typedef __attribute__((ext_vector_type(8))) short short8;
typedef __attribute__((ext_vector_type(4))) short short4v;
typedef __attribute__((ext_vector_type(4))) float floatx4;

static __device__ __forceinline__ unsigned short f2bf(float f) {
    __hip_bfloat16 h = __float2bfloat16(f);
    return *reinterpret_cast<unsigned short*>(&h);
}

static __device__ __forceinline__ short8 lds_load8(const unsigned short* p) {
    const short4v a = *(const short4v*)p;
    const short4v b = *(const short4v*)(p + 4);
    short8 r;
    r[0] = a[0]; r[1] = a[1]; r[2] = a[2]; r[3] = a[3];
    r[4] = b[0]; r[5] = b[1]; r[6] = b[2]; r[7] = b[3];
    return r;
}

// exact bf16 of a signed-byte integer (|v|<=127 -> no rounding)
static __device__ __forceinline__ unsigned cvtb(unsigned char u) {
    return (unsigned)f2bf((float)(int)(signed char)u);
}

// LDS-only barrier: drain ds ops, leave global loads (prefetch!) in flight.
// __syncthreads would emit s_waitcnt vmcnt(0) and kill the pipeline.
static __device__ __forceinline__ void lds_barrier() {
    asm volatile("s_waitcnt lgkmcnt(0)" ::: "memory");
    __builtin_amdgcn_s_barrier();
    __builtin_amdgcn_sched_barrier(0);
}

// ===================== single prep kernel (3 jobs by blockIdx range) ==================
// [0,782):   s_feats rows -> i8 quantized sfb8 (64 B/row) + rowsum (exact pairwise order)
//            + per-row scale; spts4[row] = {x,y,z, rowsum>0 ? scale : -scale}
// [782,814): wbf2 lane-linear B frags (128 KB)
// 814:       tail: zero sfb8 row N, spts4[N]=(1e6,1e6,1e6,-1), kpp
__global__ void prep_all(const float* __restrict__ sf, const float* __restrict__ w,
                         const float* __restrict__ kpts, const float* __restrict__ spt,
                         unsigned char* __restrict__ sfb8, float4* __restrict__ spts4,
                         unsigned short* __restrict__ wbf2, float4* __restrict__ kpp) {
    const int b = blockIdx.x, t = threadIdx.x;
    if (b < 782) {
        const int tt = b * 256 + t;
        const int row = tt >> 1, p = tt & 1;          // lane p covers cols 4p+8i+0..3
        if (row < NPTS) {
            const float* base = sf + (size_t)row * 64 + p * 4;
            float4 x[8];
            x[0] = *(const float4*)base;
            float4 r = x[0];
            float am = fmaxf(fmaxf(fabsf(x[0].x), fabsf(x[0].y)),
                             fmaxf(fabsf(x[0].z), fabsf(x[0].w)));
#pragma unroll
            for (int i = 1; i < 8; i++) {
                x[i] = *(const float4*)(base + i * 8);
                r.x += x[i].x; r.y += x[i].y; r.z += x[i].z; r.w += x[i].w; // strict fold
                am = fmaxf(am, fmaxf(fmaxf(fabsf(x[i].x), fabsf(x[i].y)),
                                     fmaxf(fabsf(x[i].z), fabsf(x[i].w))));
            }
            float sp = (r.x + r.y) + (r.z + r.w);
            sp += __shfl_xor(sp, 1);                  // + other half (commutative: exact)
            am = fmaxf(am, __shfl_xor(am, 1));        // row absmax (commutative: exact)
            const float inv = am > 0.0f ? 127.0f / am : 0.0f;
#pragma unroll
            for (int i = 0; i < 8; i++) {
                uchar4 o;
                o.x = (unsigned char)(int)rintf(x[i].x * inv);
                o.y = (unsigned char)(int)rintf(x[i].y * inv);
                o.z = (unsigned char)(int)rintf(x[i].z * inv);
                o.w = (unsigned char)(int)rintf(x[i].w * inv);
                *(uchar4*)&sfb8[(size_t)row * 64 + i * 8 + p * 4] = o;
            }
            if (p == 0) {
                const float sc = am * (1.0f / 127.0f);
                spts4[row] = make_float4(spt[row * 3 + 0], spt[row * 3 + 1],
                                         spt[row * 3 + 2], sp > 0.0f ? sc : -sc);
            }
        }
    } else if (b < 814) {
        const int e = (b - 782) * 256 + t;            // 0..8191
        const int lane = e & 63, s = (e >> 6) & 31, wq = e >> 11;
        const int d = wq * 16 + (lane & 15);
        const int lqp = lane >> 4;
        unsigned short o8[8];
#pragma unroll
        for (int j = 0; j < 8; j++) {
            const int kc = s * 32 + lqp * 8 + j;
            const int c = kc >> 4, k = kc & 15;
            o8[j] = (k < KK) ? f2bf(w[k * 4096 + c * 64 + d]) : (unsigned short)0;
        }
#pragma unroll
        for (int j = 0; j < 8; j++) wbf2[(size_t)e * 8 + j] = o8[j];
    } else {
        if (t < 16) *(uchar4*)&sfb8[(size_t)NPTS * 64 + t * 4] = make_uchar4(0, 0, 0, 0);
        else if (t == 16) spts4[NPTS] = make_float4(1.0e6f, 1.0e6f, 1.0e6f, -1.0f);
        else if (t >= 32 && t < 32 + KK) {
            const int k = t - 32;
            const float kx = kpts[k * 3 + 0], ky = kpts[k * 3 + 1], kz = kpts[k * 3 + 2];
            kpp[k] = make_float4(-2.f * kx, -2.f * ky, -2.f * kz, kx * kx + ky * ky + kz * kz);
        }
    }
}

// =======================================================================
// Persistent pipelined fused kernel — R9 with both measured bugs fixed:
//  (1) scratch re-aliased onto stage (LDS 53440 -> 3 blocks/CU again);
//      alias made safe by barrier 3 at loop end.
//  (2) PREFETCH(t+1) issued AFTER PHASEC's 16 wbf2 b-loads (vmcnt is a
//      FIFO: issuing the slow random gathers first made every b-load wait
//      drain them -> R9's stall). sched_barrier(0) brackets pin the order.
// Prefetch now covers barrier2 + epilogue + barrier3 + WEIGHTS (~500 cy).
// VGPR must stay <= 64 (waves/CU halves at 64) -> 24 waves/CU.
// =======================================================================
__global__ __launch_bounds__(512, 2) void kpconv_fused(
    const float* __restrict__ q_points,
    const float4* __restrict__ spts4,         // (N+1) {x,y,z, +-scale}, row N = (1e6..,-1)
    const unsigned char* __restrict__ sfb8,   // (N+1,64) i8, row N zero
    const int*   __restrict__ nbr,            // (M,32)
    const unsigned short* __restrict__ wbf2,  // lane-linear B frags (128 KB)
    const float4* __restrict__ kpp,           // (15) {-2kx,-2ky,-2kz,|kp|^2}
    float* __restrict__ out)                  // (M,64)
{
    const int t    = threadIdx.x;
    const int lane = t & 63;
    const int wv   = t >> 6;                  // 0..7
    const int l15  = lane & 15;
    const int lq   = lane >> 4;

    __shared__ __align__(16) unsigned short stage[8][64 * STPH];  // 20480 B
    __shared__ unsigned short wtw[TM * WTP];                      // 32896 B
    __shared__ float inv_lds[TM];                                 // 64 B
    // scratch aliases stage[0] (4 KB) -- safe via barrier 3 (alias race closed)

    const int mw = 2 * wv + (lane >> 5);
    const int h  = lane & 31;
    const int c4 = l15 * 4;                   // byte col in i8 row AND stage channel row

    // phase-C constants (tile-invariant)
    const int q  = wv & 3;
    const int kh = wv >> 2;
    const unsigned short* const ap = &wtw[l15 * WTP + kh * 512 + lq * 8];
    const unsigned short* const bp = wbf2 + ((size_t)((q * 32 + kh * 16) * 64) + lane) * 8;
    float* const scratch = (float*)&stage[0][0];

    unsigned short* const st = stage[wv];
    const int swzh = (l15 >> 3) << 2;         // flips slot bit2 for rows c >= 32
    const short8 zero8 = {0, 0, 0, 0, 0, 0, 0, 0};

    // pipeline registers (live across PHASEC): 16 + 4 + 3 VGPR
    uchar4 g[2][8];
    float4 sp4;
    float qx, qy, qz;

    auto PREFETCH = [&](const int m0n) {
        const int idxp = nbr[(size_t)(m0n + mw) * 32 + h];
#pragma unroll
        for (int mi = 0; mi < 2; mi++) {
            const int m = 2 * wv + mi;
#pragma unroll
            for (int g2 = 0; g2 < 4; g2++) {
                const int r0 = g2 * 8 + lq * 2;
                const int2 ip = *(const int2*)&nbr[(size_t)(m0n + m) * 32 + r0];
                const int i0 = min(ip.x, NPTS);
                const int i1 = min(ip.y, NPTS);
                g[mi][2 * g2]     = *(const uchar4*)&sfb8[(size_t)i0 * 64 + c4];
                g[mi][2 * g2 + 1] = *(const uchar4*)&sfb8[(size_t)i1 * 64 + c4];
            }
        }
        sp4 = spts4[min(idxp, NPTS)];
        qx = q_points[(m0n + mw) * 3 + 0];
        qy = q_points[(m0n + mw) * 3 + 1];
        qz = q_points[(m0n + mw) * 3 + 2];
    };

    PREFETCH(blockIdx.x * TM);

    for (int tile = blockIdx.x; tile < NTILES; tile += PGRID) {
        const int m0 = tile * TM;

        // ---- WEIGHTS: kernel-point weights (x per-row scale) + counts ----
        {
            const float rx = sp4.x - qx;
            const float ry = sp4.y - qy;
            const float rz = sp4.z - qz;
            const float r2 = rx * rx + ry * ry + rz * rz;
            const float ss = fabsf(sp4.w);    // per-row dequant scale
            unsigned short* wrow = &wtw[mw * WTP];
#pragma unroll
            for (int k = 0; k < KK; k++) {
                const float4 kp = kpp[k];             // wave-uniform -> s_load
                float d2 = kp.w;
                d2 = fmaf(rx, kp.x, d2);
                d2 = fmaf(ry, kp.y, d2);
                d2 = fmaf(rz, kp.z, d2);
                d2 = fmaxf(r2 + d2, 0.0f);            // guard tiny-negative from rounding
                const float wv_ = fmaxf(fmaf(-0.5f, __builtin_amdgcn_sqrtf(d2), 1.0f), 0.0f);
                wrow[k * STP + h] = f2bf(wv_ * ss);   // scale folded into A
            }
            wrow[15 * STP + h] = 0;                   // k-pad row

            const unsigned long long bal = __ballot(sp4.w > 0.0f);  // -0.0 > 0 is false
            if (h == 0) {
                const int cnt = __popc((unsigned)(bal >> ((lane >> 5) * 32)));
                inv_lds[mw] = 1.0f / (float)(cnt < 1 ? 1 : cnt);
            }
        }

        // ---- PHASEB: wave-private m-loop, 2 h-half rounds (consumes g) ----
#pragma unroll
        for (int mi = 0; mi < 2; mi++) {
            const int m = 2 * wv + mi;
            const short8 afull = lds_load8(&wtw[m * WTP + l15 * STP + lq * 8]);
            floatx4 d[4];
#pragma unroll
            for (int ct = 0; ct < 4; ct++) d[ct] = (floatx4){0.f, 0.f, 0.f, 0.f};
#pragma unroll
            for (int r = 0; r < 2; r++) {
#pragma unroll
                for (int g2h = 0; g2h < 2; g2h++) {
                    const int g2 = 2 * r + g2h;
                    const int so = (((g2h * 4 + lq) ^ swzh)) * 2;
                    const uchar4 a = g[mi][2 * g2];
                    const uchar4 b = g[mi][2 * g2 + 1];
                    *(unsigned*)&st[(c4 + 0) * STPH + so] = cvtb(a.x) | (cvtb(b.x) << 16);
                    *(unsigned*)&st[(c4 + 1) * STPH + so] = cvtb(a.y) | (cvtb(b.y) << 16);
                    *(unsigned*)&st[(c4 + 2) * STPH + so] = cvtb(a.z) | (cvtb(b.z) << 16);
                    *(unsigned*)&st[(c4 + 3) * STPH + so] = cvtb(a.w) | (cvtb(b.w) << 16);
                }
                const short8 ar = ((lq >> 1) == r) ? afull : zero8;
#pragma unroll
                for (int ct = 0; ct < 4; ct++) {
                    const short8 bfrag =
                        lds_load8(&st[(ct * 16 + l15) * STPH + (((lq & 1) ^ (ct >> 1)) * 8)]);
                    d[ct] = __builtin_amdgcn_mfma_f32_16x16x32_bf16(ar, bfrag, d[ct], 0, 0, 0);
                }
            }
#pragma unroll
            for (int ct = 0; ct < 4; ct++) {
                ushort4 pk;                           // raw weighted (1/cnt in epilogue)
                pk.x = f2bf(d[ct][0]); pk.y = f2bf(d[ct][1]);
                pk.z = f2bf(d[ct][2]); pk.w = f2bf(d[ct][3]);
                *(ushort4*)&wtw[m * WTP + (ct * 16 + l15) * 16 + lq * 4] = pk;
            }
        }

        lds_barrier();   // barrier 1: weighted rows + inv visible (LDS only)

        // ---- PHASEC: out[m][d] = inv[m] * sum_kc weighted[m][kc] * W''[kc][d] ----
        {
            float inv4[4];
            if (kh == 0) {
#pragma unroll
                for (int r = 0; r < 4; r++) inv4[r] = inv_lds[lq * 4 + r];  // snapshot
            }
            floatx4 acc = {0.f, 0.f, 0.f, 0.f};
#pragma unroll 8
            for (int s = 0; s < 16; s++) {
                const short8 a = lds_load8(ap + s * 32);
                const short8 b = *(const short8*)(bp + s * 512);   // issued BEFORE prefetch
                acc = __builtin_amdgcn_mfma_f32_16x16x32_bf16(a, b, acc, 0, 0, 0);
            }
            if (kh == 1) {
                *(floatx4*)&scratch[q * 256 + l15 * 16 + lq * 4] = acc;   // b128, uniform banks
            }

            // ---- PREFETCH next tile AFTER all b-loads issued (vmcnt FIFO!) ----
            __builtin_amdgcn_sched_barrier(0);        // no b-load may sink below
            const int nxt = tile + PGRID;
            if (nxt < NTILES) PREFETCH(nxt * TM);
            __builtin_amdgcn_sched_barrier(0);        // prefetch may not sink below

            lds_barrier();   // barrier 2: partials visible; wtw/stage reads drained

            if (kh == 0) {
                const floatx4 p = *(const floatx4*)&scratch[q * 256 + l15 * 16 + lq * 4];
                const int d = q * 16 + l15;
#pragma unroll
                for (int r = 0; r < 4; r++) {
                    const int m = lq * 4 + r;
                    out[(size_t)(m0 + m) * 64 + d] = (acc[r] + p[r]) * inv4[r];
                }
            }
        }

        lds_barrier();   // barrier 3: scratch reads done before next tile's stage writes
    }
}

extern "C" void kernel_launch(void* const* d_in, const int* in_sizes, int n_in,
                              void* d_out, int out_size, void* d_ws, size_t ws_size,
                              hipStream_t stream) {
    const float* q_points = (const float*)d_in[0];
    const float* s_points = (const float*)d_in[1];
    const float* s_feats  = (const float*)d_in[2];
    const int*   nbr      = (const int*)d_in[3];
    const float* weights  = (const float*)d_in[4];
    const float* kpts     = (const float*)d_in[5];
    float* out = (float*)d_out;

    char* ws = (char*)d_ws;
    unsigned short* wbf2 = (unsigned short*)ws;              // [0, 131072)
    float4* spts4 = (float4*)(ws + 131072);                  // (N+1)*16 B = 1.6 MB
    float4* kpp = (float4*)(ws + 1731088);                   // 240 B, 16B-aligned
    unsigned char* sfb8 = (unsigned char*)(ws + 1731584);    // (N+1)*64 i8 = 6.4 MB

    prep_all<<<815, 256, 0, stream>>>(s_feats, weights, kpts, s_points,
                                      sfb8, spts4, wbf2, kpp);
    kpconv_fused<<<PGRID, 512, 0, stream>>>(q_points, spts4, sfb8, nbr,
                                            wbf2, kpp, out);
}

// Round 11
// 145.471 us; speedup vs baseline: 1.0433x; 1.0433x over previous
//
#include <hip/hip_runtime.h>
#include <hip/hip_bf16.h>

#define MPTS 50000
#define NPTS 100000
#define KK 15
#define TM 16      // queries per tile; 8 waves, wave owns 2 -> barrier-free A/B phases
#define GRID ((MPTS + 31) / 32)   // 1563 blocks x 2 tiles
#define WTP 1028   // wtw row stride (shorts): 514 b32 = 2 mod 32 -> phase-C A reads uniform banks
#define STP 36     // weight-row stride inside wtw (shorts)
#define STPH 20    // half-h stage row stride (shorts): 40 B rows (8B-aligned)

typedef __attribute__((ext_vector_type(8))) short short8;
typedef __attribute__((ext_vector_type(4))) short short4v;
typedef __attribute__((ext_vector_type(4))) float floatx4;

static __device__ __forceinline__ unsigned short f2bf(float f) {
    __hip_bfloat16 h = __float2bfloat16(f);
    return *reinterpret_cast<unsigned short*>(&h);
}

static __device__ __forceinline__ short8 lds_load8(const unsigned short* p) {
    const short4v a = *(const short4v*)p;
    const short4v b = *(const short4v*)(p + 4);
    short8 r;
    r[0] = a[0]; r[1] = a[1]; r[2] = a[2]; r[3] = a[3];
    r[4] = b[0]; r[5] = b[1]; r[6] = b[2]; r[7] = b[3];
    return r;
}

// exact bf16 of a signed-byte integer (|v|<=127 -> no rounding)
static __device__ __forceinline__ unsigned cvtb(unsigned char u) {
    return (unsigned)f2bf((float)(int)(signed char)u);
}

// LDS-only barrier: drain ds ops, leave global loads (tile-b gathers!) in flight.
static __device__ __forceinline__ void lds_barrier() {
    asm volatile("s_waitcnt lgkmcnt(0)" ::: "memory");
    __builtin_amdgcn_s_barrier();
    __builtin_amdgcn_sched_barrier(0);
}

// ===================== single prep kernel (3 jobs by blockIdx range) ==================
// [0,782):   s_feats rows -> i8 quantized sfb8 (64 B/row) + rowsum (exact pairwise order)
//            + per-row scale; spts4[row] = {x,y,z, rowsum>0 ? scale : -scale}
// [782,814): wbf2 lane-linear B frags (128 KB)
// 814:       tail: zero sfb8 row N, spts4[N]=(1e6,1e6,1e6,-1), kpp
__global__ void prep_all(const float* __restrict__ sf, const float* __restrict__ w,
                         const float* __restrict__ kpts, const float* __restrict__ spt,
                         unsigned char* __restrict__ sfb8, float4* __restrict__ spts4,
                         unsigned short* __restrict__ wbf2, float4* __restrict__ kpp) {
    const int b = blockIdx.x, t = threadIdx.x;
    if (b < 782) {
        const int tt = b * 256 + t;
        const int row = tt >> 1, p = tt & 1;          // lane p covers cols 4p+8i+0..3
        if (row < NPTS) {
            const float* base = sf + (size_t)row * 64 + p * 4;
            float4 x[8];
            x[0] = *(const float4*)base;
            float4 r = x[0];
            float am = fmaxf(fmaxf(fabsf(x[0].x), fabsf(x[0].y)),
                             fmaxf(fabsf(x[0].z), fabsf(x[0].w)));
#pragma unroll
            for (int i = 1; i < 8; i++) {
                x[i] = *(const float4*)(base + i * 8);
                r.x += x[i].x; r.y += x[i].y; r.z += x[i].z; r.w += x[i].w; // strict fold
                am = fmaxf(am, fmaxf(fmaxf(fabsf(x[i].x), fabsf(x[i].y)),
                                     fmaxf(fabsf(x[i].z), fabsf(x[i].w))));
            }
            float sp = (r.x + r.y) + (r.z + r.w);
            sp += __shfl_xor(sp, 1);                  // + other half (commutative: exact)
            am = fmaxf(am, __shfl_xor(am, 1));        // row absmax (commutative: exact)
            const float inv = am > 0.0f ? 127.0f / am : 0.0f;
#pragma unroll
            for (int i = 0; i < 8; i++) {
                uchar4 o;
                o.x = (unsigned char)(int)rintf(x[i].x * inv);
                o.y = (unsigned char)(int)rintf(x[i].y * inv);
                o.z = (unsigned char)(int)rintf(x[i].z * inv);
                o.w = (unsigned char)(int)rintf(x[i].w * inv);
                *(uchar4*)&sfb8[(size_t)row * 64 + i * 8 + p * 4] = o;
            }
            if (p == 0) {
                const float sc = am * (1.0f / 127.0f);
                spts4[row] = make_float4(spt[row * 3 + 0], spt[row * 3 + 1],
                                         spt[row * 3 + 2], sp > 0.0f ? sc : -sc);
            }
        }
    } else if (b < 814) {
        const int e = (b - 782) * 256 + t;            // 0..8191
        const int lane = e & 63, s = (e >> 6) & 31, wq = e >> 11;
        const int d = wq * 16 + (lane & 15);
        const int lqp = lane >> 4;
        unsigned short o8[8];
#pragma unroll
        for (int j = 0; j < 8; j++) {
            const int kc = s * 32 + lqp * 8 + j;
            const int c = kc >> 4, k = kc & 15;
            o8[j] = (k < KK) ? f2bf(w[k * 4096 + c * 64 + d]) : (unsigned short)0;
        }
#pragma unroll
        for (int j = 0; j < 8; j++) wbf2[(size_t)e * 8 + j] = o8[j];
    } else {
        if (t < 16) *(uchar4*)&sfb8[(size_t)NPTS * 64 + t * 4] = make_uchar4(0, 0, 0, 0);
        else if (t == 16) spts4[NPTS] = make_float4(1.0e6f, 1.0e6f, 1.0e6f, -1.0f);
        else if (t >= 32 && t < 32 + KK) {
            const int k = t - 32;
            const float kx = kpts[k * 3 + 0], ky = kpts[k * 3 + 1], kz = kpts[k * 3 + 2];
            kpp[k] = make_float4(-2.f * kx, -2.f * ky, -2.f * kz, kx * kx + ky * ky + kz * kz);
        }
    }
}

// =======================================================================
// Fused main kernel: R8 structure, TWO tiles per block, ALL loads issued
// at block entry in order g(a) -> g(b) -> [phase-C b-loads(a)].
// FIFO property: PHASEB(a)'s g(a)-waits don't drain g(b) (issued after);
// PHASEC(a)'s first b-load wait forces g(b) complete, but only after
// WEIGHTS(a)+PHASEB(a)+barrier (~1300 cy) -- HBM misses retired by then.
// => tile-b's gather latency fully hidden; wbf2 stream halved.
// NON-persistent (1563 blocks): block turnover keeps cross-block overlap.
// LDS: stage 20480 + wtw 32896 + inv 64 = 53440 -> 3 blocks/CU.
// __launch_bounds__(512,3): arg2=min-BLOCKS (R7-measured) -> ~80-VGPR cap
// while guaranteeing 24 waves/CU.
// =======================================================================
__global__ __launch_bounds__(512, 3) void kpconv_fused(
    const float* __restrict__ q_points,
    const float4* __restrict__ spts4,         // (N+1) {x,y,z, +-scale}, row N = (1e6..,-1)
    const unsigned char* __restrict__ sfb8,   // (N+1,64) i8, row N zero
    const int*   __restrict__ nbr,            // (M,32)
    const unsigned short* __restrict__ wbf2,  // lane-linear B frags (128 KB)
    const float4* __restrict__ kpp,           // (15) {-2kx,-2ky,-2kz,|kp|^2}
    float* __restrict__ out)                  // (M,64)
{
    const int t    = threadIdx.x;
    const int lane = t & 63;
    const int wv   = t >> 6;                  // 0..7
    const int l15  = lane & 15;
    const int lq   = lane >> 4;

    __shared__ __align__(16) unsigned short stage[8][64 * STPH];  // 20480 B
    __shared__ unsigned short wtw[TM * WTP];                      // 32896 B
    __shared__ float inv_lds[TM];
    // scratch aliases stage[0]: staged data is dead by the time kh==1 writes it

    const int mw = 2 * wv + (lane >> 5);
    const int h  = lane & 31;
    const int c4 = l15 * 4;                   // byte col in i8 row AND stage channel row

    // phase-C constants (tile-invariant)
    const int q  = wv & 3;
    const int kh = wv >> 2;
    const unsigned short* const ap = &wtw[l15 * WTP + kh * 512 + lq * 8];
    const unsigned short* const bp = wbf2 + ((size_t)((q * 32 + kh * 16) * 64) + lane) * 8;
    float* const scratch = (float*)&stage[0][0];

    unsigned short* const st = stage[wv];
    const int swzh = (l15 >> 3) << 2;         // flips slot bit2 for rows c >= 32
    const short8 zero8 = {0, 0, 0, 0, 0, 0, 0, 0};

    const int m0a = blockIdx.x * 32;          // tile a: rows m0a..m0a+15 (always valid)
    const int m0b = m0a + 16;                 // tile b: may exceed MPTS (last block)

    // ================= PRE: issue ALL loads, tile a strictly before tile b =========
    const int ia = nbr[(size_t)(m0a + mw) * 32 + h];
    const float4 sp4a = spts4[min(ia, NPTS)];
    uchar4 ga[2][8];
#pragma unroll
    for (int mi = 0; mi < 2; mi++) {
        const int m = 2 * wv + mi;
#pragma unroll
        for (int g2 = 0; g2 < 4; g2++) {
            const int r0 = g2 * 8 + lq * 2;
            const int2 ip = *(const int2*)&nbr[(size_t)(m0a + m) * 32 + r0];
            ga[mi][2 * g2]     = *(const uchar4*)&sfb8[(size_t)min(ip.x, NPTS) * 64 + c4];
            ga[mi][2 * g2 + 1] = *(const uchar4*)&sfb8[(size_t)min(ip.y, NPTS) * 64 + c4];
        }
    }
    const float qax = q_points[(m0a + mw) * 3 + 0];
    const float qay = q_points[(m0a + mw) * 3 + 1];
    const float qaz = q_points[(m0a + mw) * 3 + 2];

    const int mrb = min(m0b + mw, MPTS - 1);  // clamped for the tail block
    const int ib = nbr[(size_t)mrb * 32 + h];
    const float4 sp4b = spts4[min(ib, NPTS)];
    uchar4 gb[2][8];
#pragma unroll
    for (int mi = 0; mi < 2; mi++) {
        const int m = min(m0b + 2 * wv + mi, MPTS - 1);
#pragma unroll
        for (int g2 = 0; g2 < 4; g2++) {
            const int r0 = g2 * 8 + lq * 2;
            const int2 ip = *(const int2*)&nbr[(size_t)m * 32 + r0];
            gb[mi][2 * g2]     = *(const uchar4*)&sfb8[(size_t)min(ip.x, NPTS) * 64 + c4];
            gb[mi][2 * g2 + 1] = *(const uchar4*)&sfb8[(size_t)min(ip.y, NPTS) * 64 + c4];
        }
    }
    const float qbx = q_points[mrb * 3 + 0];
    const float qby = q_points[mrb * 3 + 1];
    const float qbz = q_points[mrb * 3 + 2];

    // ---- WEIGHTS: kernel-point weights (x per-row scale) + counts -> wtw, inv ----
    auto WEIGHTS = [&](const float4 sp4, const float qx, const float qy, const float qz) {
        const float rx = sp4.x - qx;
        const float ry = sp4.y - qy;
        const float rz = sp4.z - qz;
        const float r2 = rx * rx + ry * ry + rz * rz;
        const float ss = fabsf(sp4.w);        // per-row dequant scale
        unsigned short* wrow = &wtw[mw * WTP];
#pragma unroll
        for (int k = 0; k < KK; k++) {
            const float4 kp = kpp[k];         // wave-uniform -> s_load
            float d2 = kp.w;
            d2 = fmaf(rx, kp.x, d2);
            d2 = fmaf(ry, kp.y, d2);
            d2 = fmaf(rz, kp.z, d2);
            d2 = fmaxf(r2 + d2, 0.0f);        // guard tiny-negative from rounding
            const float wv_ = fmaxf(fmaf(-0.5f, __builtin_amdgcn_sqrtf(d2), 1.0f), 0.0f);
            wrow[k * STP + h] = f2bf(wv_ * ss);   // scale folded into A
        }
        wrow[15 * STP + h] = 0;               // k-pad row

        const unsigned long long bal = __ballot(sp4.w > 0.0f);  // -0.0 > 0 is false
        if (h == 0) {
            const int cnt = __popc((unsigned)(bal >> ((lane >> 5) * 32)));
            inv_lds[mw] = 1.0f / (float)(cnt < 1 ? 1 : cnt);
        }
    };

    // ---- PHASEB: wave-private m-loop, 2 h-half rounds (consumes one g set) ----
    auto PHASEB = [&](const uchar4 (&g)[2][8]) {
#pragma unroll
        for (int mi = 0; mi < 2; mi++) {
            const int m = 2 * wv + mi;
            const short8 afull = lds_load8(&wtw[m * WTP + l15 * STP + lq * 8]);
            floatx4 d[4];
#pragma unroll
            for (int ct = 0; ct < 4; ct++) d[ct] = (floatx4){0.f, 0.f, 0.f, 0.f};
#pragma unroll
            for (int r = 0; r < 2; r++) {
#pragma unroll
                for (int g2h = 0; g2h < 2; g2h++) {
                    const int g2 = 2 * r + g2h;
                    const int so = (((g2h * 4 + lq) ^ swzh)) * 2;
                    const uchar4 a = g[mi][2 * g2];
                    const uchar4 b = g[mi][2 * g2 + 1];
                    *(unsigned*)&st[(c4 + 0) * STPH + so] = cvtb(a.x) | (cvtb(b.x) << 16);
                    *(unsigned*)&st[(c4 + 1) * STPH + so] = cvtb(a.y) | (cvtb(b.y) << 16);
                    *(unsigned*)&st[(c4 + 2) * STPH + so] = cvtb(a.z) | (cvtb(b.z) << 16);
                    *(unsigned*)&st[(c4 + 3) * STPH + so] = cvtb(a.w) | (cvtb(b.w) << 16);
                }
                const short8 ar = ((lq >> 1) == r) ? afull : zero8;
#pragma unroll
                for (int ct = 0; ct < 4; ct++) {
                    const short8 bfrag =
                        lds_load8(&st[(ct * 16 + l15) * STPH + (((lq & 1) ^ (ct >> 1)) * 8)]);
                    d[ct] = __builtin_amdgcn_mfma_f32_16x16x32_bf16(ar, bfrag, d[ct], 0, 0, 0);
                }
            }
#pragma unroll
            for (int ct = 0; ct < 4; ct++) {
                ushort4 pk;                   // raw weighted (1/cnt in epilogue)
                pk.x = f2bf(d[ct][0]); pk.y = f2bf(d[ct][1]);
                pk.z = f2bf(d[ct][2]); pk.w = f2bf(d[ct][3]);
                *(ushort4*)&wtw[m * WTP + (ct * 16 + l15) * 16 + lq * 4] = pk;
            }
        }
    };

    // ---- PHASEC + epilogue: out = inv * weighted x W'' (split-K over kh) ----
    auto PHASEC = [&](const int m0, const bool store_ok) {
        float inv4[4];
        if (kh == 0) {
#pragma unroll
            for (int r = 0; r < 4; r++) inv4[r] = inv_lds[lq * 4 + r];  // snapshot
        }
        floatx4 acc = {0.f, 0.f, 0.f, 0.f};
#pragma unroll 8
        for (int s = 0; s < 16; s++) {
            const short8 a = lds_load8(ap + s * 32);
            const short8 b = *(const short8*)(bp + s * 512);   // coalesced, L2-hot
            acc = __builtin_amdgcn_mfma_f32_16x16x32_bf16(a, b, acc, 0, 0, 0);
        }
        if (kh == 1) {
            *(floatx4*)&scratch[q * 256 + l15 * 16 + lq * 4] = acc;   // b128, uniform banks
        }
        __syncthreads();   // partials visible; wtw/stage reads drained
        if (kh == 0 && store_ok) {
            const floatx4 p = *(const floatx4*)&scratch[q * 256 + l15 * 16 + lq * 4];
            const int d = q * 16 + l15;
#pragma unroll
            for (int r = 0; r < 4; r++) {
                const int m = m0 + lq * 4 + r;
                if (m < MPTS)
                    out[(size_t)m * 64 + d] = (acc[r] + p[r]) * inv4[r];
            }
        }
    };

    // ================================ tile a =====================================
    WEIGHTS(sp4a, qax, qay, qaz);
    PHASEB(ga);
    lds_barrier();        // LDS-only: gb stays in flight across this barrier!
    PHASEC(m0a, true);

    // ================================ tile b =====================================
    // WEIGHTS(b) may write wtw immediately: all PHASEC(a) wtw reads pre-date the
    // __syncthreads inside PHASEC. Epilogue(a) scratch reads vs PHASEB(b) stage
    // writes are ordered by the __syncthreads below.
    WEIGHTS(sp4b, qbx, qby, qbz);
    __syncthreads();      // scratch(a) reads done before stage(b) writes
    PHASEB(gb);
    __syncthreads();      // weighted(b) rows + inv(b) visible
    PHASEC(m0b, true);    // per-store m < MPTS guard handles the tail block
}

extern "C" void kernel_launch(void* const* d_in, const int* in_sizes, int n_in,
                              void* d_out, int out_size, void* d_ws, size_t ws_size,
                              hipStream_t stream) {
    const float* q_points = (const float*)d_in[0];
    const float* s_points = (const float*)d_in[1];
    const float* s_feats  = (const float*)d_in[2];
    const int*   nbr      = (const int*)d_in[3];
    const float* weights  = (const float*)d_in[4];
    const float* kpts     = (const float*)d_in[5];
    float* out = (float*)d_out;

    char* ws = (char*)d_ws;
    unsigned short* wbf2 = (unsigned short*)ws;              // [0, 131072)
    float4* spts4 = (float4*)(ws + 131072);                  // (N+1)*16 B = 1.6 MB
    float4* kpp = (float4*)(ws + 1731088);                   // 240 B, 16B-aligned
    unsigned char* sfb8 = (unsigned char*)(ws + 1731584);    // (N+1)*64 i8 = 6.4 MB

    prep_all<<<815, 256, 0, stream>>>(s_feats, weights, kpts, s_points,
                                      sfb8, spts4, wbf2, kpp);
    kpconv_fused<<<GRID, 512, 0, stream>>>(q_points, spts4, sfb8, nbr,
                                           wbf2, kpp, out);
}

// Round 12
// 134.772 us; speedup vs baseline: 1.1261x; 1.0794x over previous
//
#include <hip/hip_runtime.h>
#include <hip/hip_bf16.h>

#define MPTS 50000
#define NPTS 100000
#define KK 15
#define TM 16      // queries per tile; 8 waves, wave owns 2 -> barrier-free A/B phases
#define WTP 1028   // wtw row stride (shorts): 514 b32 = 2 mod 32 -> phase-C A reads uniform banks
#define STP 36     // weight-row stride inside wtw (shorts)
#define STPH 20    // half-h stage row stride (shorts): 40 B rows (8B-aligned)

typedef __attribute__((ext_vector_type(8))) short short8;
typedef __attribute__((ext_vector_type(4))) short short4v;
typedef __attribute__((ext_vector_type(4))) float floatx4;

static __device__ __forceinline__ unsigned short f2bf(float f) {
    __hip_bfloat16 h = __float2bfloat16(f);
    return *reinterpret_cast<unsigned short*>(&h);
}

static __device__ __forceinline__ short8 lds_load8(const unsigned short* p) {
    const short4v a = *(const short4v*)p;
    const short4v b = *(const short4v*)(p + 4);
    short8 r;
    r[0] = a[0]; r[1] = a[1]; r[2] = a[2]; r[3] = a[3];
    r[4] = b[0]; r[5] = b[1]; r[6] = b[2]; r[7] = b[3];
    return r;
}

// exact bf16 of a signed-byte integer (|v|<=127 -> no rounding)
static __device__ __forceinline__ unsigned cvtb(unsigned char u) {
    return (unsigned)f2bf((float)(int)(signed char)u);
}

// ===================== single prep kernel (3 jobs by blockIdx range) ==================
// [0,782):   s_feats rows -> i8 quantized sfb8 (64 B/row) + rowsum (exact pairwise order)
//            + per-row scale; spts4[row] = {x,y,z, rowsum>0 ? scale : -scale}
// [782,814): wbf2 lane-linear B frags (128 KB)
// 814:       tail: zero sfb8 row N, spts4[N]=(1e6,1e6,1e6,-1), kpp
__global__ void prep_all(const float* __restrict__ sf, const float* __restrict__ w,
                         const float* __restrict__ kpts, const float* __restrict__ spt,
                         unsigned char* __restrict__ sfb8, float4* __restrict__ spts4,
                         unsigned short* __restrict__ wbf2, float4* __restrict__ kpp) {
    const int b = blockIdx.x, t = threadIdx.x;
    if (b < 782) {
        const int tt = b * 256 + t;
        const int row = tt >> 1, p = tt & 1;          // lane p covers cols 4p+8i+0..3
        if (row < NPTS) {
            const float* base = sf + (size_t)row * 64 + p * 4;
            float4 x[8];
            x[0] = *(const float4*)base;
            float4 r = x[0];
            float am = fmaxf(fmaxf(fabsf(x[0].x), fabsf(x[0].y)),
                             fmaxf(fabsf(x[0].z), fabsf(x[0].w)));
#pragma unroll
            for (int i = 1; i < 8; i++) {
                x[i] = *(const float4*)(base + i * 8);
                r.x += x[i].x; r.y += x[i].y; r.z += x[i].z; r.w += x[i].w; // strict fold
                am = fmaxf(am, fmaxf(fmaxf(fabsf(x[i].x), fabsf(x[i].y)),
                                     fmaxf(fabsf(x[i].z), fabsf(x[i].w))));
            }
            float sp = (r.x + r.y) + (r.z + r.w);
            sp += __shfl_xor(sp, 1);                  // + other half (commutative: exact)
            am = fmaxf(am, __shfl_xor(am, 1));        // row absmax (commutative: exact)
            const float inv = am > 0.0f ? 127.0f / am : 0.0f;
#pragma unroll
            for (int i = 0; i < 8; i++) {
                uchar4 o;
                o.x = (unsigned char)(int)rintf(x[i].x * inv);
                o.y = (unsigned char)(int)rintf(x[i].y * inv);
                o.z = (unsigned char)(int)rintf(x[i].z * inv);
                o.w = (unsigned char)(int)rintf(x[i].w * inv);
                *(uchar4*)&sfb8[(size_t)row * 64 + i * 8 + p * 4] = o;
            }
            if (p == 0) {
                const float sc = am * (1.0f / 127.0f);
                spts4[row] = make_float4(spt[row * 3 + 0], spt[row * 3 + 1],
                                         spt[row * 3 + 2], sp > 0.0f ? sc : -sc);
            }
        }
    } else if (b < 814) {
        const int e = (b - 782) * 256 + t;            // 0..8191
        const int lane = e & 63, s = (e >> 6) & 31, wq = e >> 11;
        const int d = wq * 16 + (lane & 15);
        const int lqp = lane >> 4;
        unsigned short o8[8];
#pragma unroll
        for (int j = 0; j < 8; j++) {
            const int kc = s * 32 + lqp * 8 + j;
            const int c = kc >> 4, k = kc & 15;
            o8[j] = (k < KK) ? f2bf(w[k * 4096 + c * 64 + d]) : (unsigned short)0;
        }
#pragma unroll
        for (int j = 0; j < 8; j++) wbf2[(size_t)e * 8 + j] = o8[j];
    } else {
        if (t < 16) *(uchar4*)&sfb8[(size_t)NPTS * 64 + t * 4] = make_uchar4(0, 0, 0, 0);
        else if (t == 16) spts4[NPTS] = make_float4(1.0e6f, 1.0e6f, 1.0e6f, -1.0f);
        else if (t >= 32 && t < 32 + KK) {
            const int k = t - 32;
            const float kx = kpts[k * 3 + 0], ky = kpts[k * 3 + 1], kz = kpts[k * 3 + 2];
            kpp[k] = make_float4(-2.f * kx, -2.f * ky, -2.f * kz, kx * kx + ky * ky + kz * kz);
        }
    }
}

// =======================================================================
// Fused main kernel (R8: the session's verified best — 47.5 us fused).
// TM=16, 512 threads, NON-persistent (6250 blocks, 3 resident/CU): block
// turnover provides the cross-tile latency overlap that every explicit
// intra-block pipeline variant (persistent loop, lgkm-only barriers,
// FIFO-ordered prefetch, two-tile batching) measurably destroyed.
// Features gathered as 64 B i8 rows (footprint 6.4 MB: ~2x L2 hit rate,
// half the gather bytes vs bf16). Dequant is EXACT: B frag = bf16(int8);
// per-row scale folded into A: bf16(w_kh * s_h). LDS: stage 20480 +
// wtw 32896 + inv 64 = 53440 B -> 3 blocks/CU; scratch aliases stage
// (safe: stage is dead after barrier 1, kernel ends after phase C).
// =======================================================================
__global__ __launch_bounds__(512, 2) void kpconv_fused(
    const float* __restrict__ q_points,
    const float4* __restrict__ spts4,         // (N+1) {x,y,z, +-scale}, row N = (1e6..,-1)
    const unsigned char* __restrict__ sfb8,   // (N+1,64) i8, row N zero
    const int*   __restrict__ nbr,            // (M,32)
    const unsigned short* __restrict__ wbf2,  // lane-linear B frags (128 KB)
    const float4* __restrict__ kpp,           // (15) {-2kx,-2ky,-2kz,|kp|^2}
    float* __restrict__ out)                  // (M,64)
{
    const int t    = threadIdx.x;
    const int m0   = blockIdx.x * TM;
    const int lane = t & 63;
    const int wv   = t >> 6;                  // 0..7
    const int l15  = lane & 15;
    const int lq   = lane >> 4;

    __shared__ __align__(16) unsigned short stage[8][64 * STPH];  // 20480 B
    __shared__ unsigned short wtw[TM * WTP];                      // 32896 B
    __shared__ float inv_lds[TM];

    const int mw = 2 * wv + (lane >> 5);
    const int h  = lane & 31;
    const int c4 = l15 * 4;                   // byte col in i8 row AND stage channel row

    // ---- per-lane neighbor index + merged point/scale gather ----
    const int idxp = nbr[(size_t)(m0 + mw) * 32 + h];
    const float4 sp4 = spts4[min(idxp, NPTS)];

    // ---- issue BOTH m feature gathers (16 x 4B i8, rows paired per lane slot) ----
    uchar4 g[2][8];
#pragma unroll
    for (int mi = 0; mi < 2; mi++) {
        const int m = 2 * wv + mi;
#pragma unroll
        for (int g2 = 0; g2 < 4; g2++) {
            const int r0 = g2 * 8 + lq * 2;
            const int2 ip = *(const int2*)&nbr[(size_t)(m0 + m) * 32 + r0];
            const int i0 = min(ip.x, NPTS);
            const int i1 = min(ip.y, NPTS);
            g[mi][2 * g2]     = *(const uchar4*)&sfb8[(size_t)i0 * 64 + c4];
            g[mi][2 * g2 + 1] = *(const uchar4*)&sfb8[(size_t)i1 * 64 + c4];
        }
    }

    // ---- kernel-point weights (x per-row scale) + counts ----
    {
        const float rx = sp4.x - q_points[(m0 + mw) * 3 + 0];
        const float ry = sp4.y - q_points[(m0 + mw) * 3 + 1];
        const float rz = sp4.z - q_points[(m0 + mw) * 3 + 2];
        const float r2 = rx * rx + ry * ry + rz * rz;
        const float ss = fabsf(sp4.w);        // per-row dequant scale
        unsigned short* wrow = &wtw[mw * WTP];
#pragma unroll
        for (int k = 0; k < KK; k++) {
            const float4 kp = kpp[k];                 // wave-uniform -> s_load
            float d2 = kp.w;
            d2 = fmaf(rx, kp.x, d2);
            d2 = fmaf(ry, kp.y, d2);
            d2 = fmaf(rz, kp.z, d2);
            d2 = fmaxf(r2 + d2, 0.0f);                // guard tiny-negative from rounding
            const float wv_ = fmaxf(fmaf(-0.5f, __builtin_amdgcn_sqrtf(d2), 1.0f), 0.0f);
            wrow[k * STP + h] = f2bf(wv_ * ss);       // scale folded into A
        }
        wrow[15 * STP + h] = 0;                       // k-pad row

        const unsigned long long bal = __ballot(sp4.w > 0.0f);  // -0.0 > 0 is false
        if (h == 0) {
            const int cnt = __popc((unsigned)(bal >> ((lane >> 5) * 32)));
            inv_lds[mw] = 1.0f / (float)(cnt < 1 ? 1 : cnt);
        }
    }

    // ---- wave-private m-loop, 2 h-half rounds each (half stage, i8->bf16 in stage) ----
    unsigned short* const st = stage[wv];
    const int swzh = (l15 >> 3) << 2;                 // flips slot bit2 for rows c >= 32
    const short8 zero8 = {0, 0, 0, 0, 0, 0, 0, 0};
#pragma unroll
    for (int mi = 0; mi < 2; mi++) {
        const int m = 2 * wv + mi;
        const short8 afull = lds_load8(&wtw[m * WTP + l15 * STP + lq * 8]);
        floatx4 d[4];
#pragma unroll
        for (int ct = 0; ct < 4; ct++) d[ct] = (floatx4){0.f, 0.f, 0.f, 0.f};
#pragma unroll
        for (int r = 0; r < 2; r++) {
#pragma unroll
            for (int g2h = 0; g2h < 2; g2h++) {
                const int g2 = 2 * r + g2h;
                const int so = (((g2h * 4 + lq) ^ swzh)) * 2;
                const uchar4 a = g[mi][2 * g2];
                const uchar4 b = g[mi][2 * g2 + 1];
                *(unsigned*)&st[(c4 + 0) * STPH + so] = cvtb(a.x) | (cvtb(b.x) << 16);
                *(unsigned*)&st[(c4 + 1) * STPH + so] = cvtb(a.y) | (cvtb(b.y) << 16);
                *(unsigned*)&st[(c4 + 2) * STPH + so] = cvtb(a.z) | (cvtb(b.z) << 16);
                *(unsigned*)&st[(c4 + 3) * STPH + so] = cvtb(a.w) | (cvtb(b.w) << 16);
            }
            const short8 ar = ((lq >> 1) == r) ? afull : zero8;
#pragma unroll
            for (int ct = 0; ct < 4; ct++) {
                const short8 bfrag =
                    lds_load8(&st[(ct * 16 + l15) * STPH + (((lq & 1) ^ (ct >> 1)) * 8)]);
                d[ct] = __builtin_amdgcn_mfma_f32_16x16x32_bf16(ar, bfrag, d[ct], 0, 0, 0);
            }
        }
#pragma unroll
        for (int ct = 0; ct < 4; ct++) {
            ushort4 pk;                               // raw weighted (1/cnt in epilogue)
            pk.x = f2bf(d[ct][0]); pk.y = f2bf(d[ct][1]);
            pk.z = f2bf(d[ct][2]); pk.w = f2bf(d[ct][3]);
            *(ushort4*)&wtw[m * WTP + (ct * 16 + l15) * 16 + lq * 4] = pk;
        }
    }
    __syncthreads();   // barrier 1: all 16 weighted rows + inv visible

    // ---- Phase C: out[m][d] = inv[m] * sum_kc weighted[m][kc] * W''[kc][d] ----
    {
        const int q  = wv & 3;
        const int kh = wv >> 2;
        floatx4 acc = {0.f, 0.f, 0.f, 0.f};
        const unsigned short* ap = &wtw[l15 * WTP + kh * 512 + lq * 8];
        const unsigned short* bp = wbf2 + ((size_t)((q * 32 + kh * 16) * 64) + lane) * 8;
#pragma unroll 8
        for (int s = 0; s < 16; s++) {
            const short8 a = lds_load8(ap + s * 32);
            const short8 b = *(const short8*)(bp + s * 512);   // coalesced, L2-hot
            acc = __builtin_amdgcn_mfma_f32_16x16x32_bf16(a, b, acc, 0, 0, 0);
        }

        // split-K reduction through the dead stage region (4 KB; safe: kernel ends)
        float* const scratch = (float*)&stage[0][0];
        if (kh == 1) {
            *(floatx4*)&scratch[q * 256 + l15 * 16 + lq * 4] = acc;   // b128, uniform banks
        }
        __syncthreads();   // barrier 2: partials visible
        if (kh == 0) {
            const floatx4 p = *(const floatx4*)&scratch[q * 256 + l15 * 16 + lq * 4];
            const int d = q * 16 + l15;
#pragma unroll
            for (int r = 0; r < 4; r++) {
                const int m = lq * 4 + r;
                out[(size_t)(m0 + m) * 64 + d] = (acc[r] + p[r]) * inv_lds[m];
            }
        }
    }
}

extern "C" void kernel_launch(void* const* d_in, const int* in_sizes, int n_in,
                              void* d_out, int out_size, void* d_ws, size_t ws_size,
                              hipStream_t stream) {
    const float* q_points = (const float*)d_in[0];
    const float* s_points = (const float*)d_in[1];
    const float* s_feats  = (const float*)d_in[2];
    const int*   nbr      = (const int*)d_in[3];
    const float* weights  = (const float*)d_in[4];
    const float* kpts     = (const float*)d_in[5];
    float* out = (float*)d_out;

    char* ws = (char*)d_ws;
    unsigned short* wbf2 = (unsigned short*)ws;              // [0, 131072)
    float4* spts4 = (float4*)(ws + 131072);                  // (N+1)*16 B = 1.6 MB
    float4* kpp = (float4*)(ws + 1731088);                   // 240 B, 16B-aligned
    unsigned char* sfb8 = (unsigned char*)(ws + 1731584);    // (N+1)*64 i8 = 6.4 MB

    prep_all<<<815, 256, 0, stream>>>(s_feats, weights, kpts, s_points,
                                      sfb8, spts4, wbf2, kpp);
    kpconv_fused<<<MPTS / TM, 512, 0, stream>>>(q_points, spts4, sfb8, nbr,
                                                wbf2, kpp, out);
}